// Round 1
// baseline (748.266 us; speedup 1.0000x reference)
//
#include <hip/hip_runtime.h>

#define T_SEQ 2048
#define MDL   1024
#define NH    8
#define HD    128

typedef __bf16 bf16;
typedef __bf16 bf16x8 __attribute__((ext_vector_type(8)));
typedef __bf16 bf16x4 __attribute__((ext_vector_type(4)));
typedef float  f32x4  __attribute__((ext_vector_type(4)));

// ---------------------------------------------------------------------------
// Kernel 1: QKV projection GEMM (fp32 inputs -> bf16 LDS tiles -> MFMA) with
// fused fractional RoPE in the epilogue. Output: Q,K,V bf16 [B,H,T,D].
// C = x[4096,1024] @ Wqkv[1024,3072]; each 128-wide n-tile is exactly one
// (section,h) pair since 1024 % 128 == 0.
// ---------------------------------------------------------------------------
__global__ __launch_bounds__(256) void qkv_rope_kernel(
    const float* __restrict__ x,  const float* __restrict__ wq,
    const float* __restrict__ wk, const float* __restrict__ wv,
    bf16* __restrict__ Qb, bf16* __restrict__ Kb, bf16* __restrict__ Vb)
{
    __shared__ bf16 a_lds[128 * 40];   // A tile [m][k], row stride 40 (pad)
    __shared__ bf16 b_lds[128 * 40];   // B tile transposed [n][k], stride 40

    const int tid  = threadIdx.x;
    const int bx   = blockIdx.x;
    const int nt   = bx % 24, mt = bx / 24;
    const int n0   = nt * 128, m0 = mt * 128;
    const int section = n0 >> 10;            // 0=q, 1=k, 2=v
    const int h       = (n0 & 1023) >> 7;    // head
    const float* Bg = (section == 0 ? wq : (section == 1 ? wk : wv)) + h * HD;

    const int lane = tid & 63, w = tid >> 6;
    const int quad = lane >> 4, l15 = lane & 15;
    const int wr = w >> 1, wc = w & 1;

    // staging maps
    const int am = tid & 127, ac0 = (tid >> 7) * 16;   // A: row am, 16 cols
    const int bk = tid & 31,  bc0 = (tid >> 5) * 16;   // B: k-row bk, 16 n-cols

    f32x4 acc[4][4] = {};

    for (int k0 = 0; k0 < MDL; k0 += 32) {
        // ---- stage A (fp32 -> bf16) ----
        const float* ap = x + (m0 + am) * MDL + k0 + ac0;
        #pragma unroll
        for (int i = 0; i < 4; ++i) {
            float4 v = *(const float4*)(ap + 4 * i);
            bf16x4 o; o[0] = (bf16)v.x; o[1] = (bf16)v.y; o[2] = (bf16)v.z; o[3] = (bf16)v.w;
            *(bf16x4*)&a_lds[am * 40 + ac0 + 4 * i] = o;
        }
        // ---- stage B transposed (fp32 -> bf16) ----
        const float* bp = Bg + (size_t)(k0 + bk) * MDL + bc0;
        #pragma unroll
        for (int i = 0; i < 4; ++i) {
            float4 v = *(const float4*)(bp + 4 * i);
            b_lds[(bc0 + 4 * i + 0) * 40 + bk] = (bf16)v.x;
            b_lds[(bc0 + 4 * i + 1) * 40 + bk] = (bf16)v.y;
            b_lds[(bc0 + 4 * i + 2) * 40 + bk] = (bf16)v.z;
            b_lds[(bc0 + 4 * i + 3) * 40 + bk] = (bf16)v.w;
        }
        __syncthreads();

        bf16x8 af[4], bfr[4];
        #pragma unroll
        for (int mi = 0; mi < 4; ++mi)
            af[mi] = *(const bf16x8*)&a_lds[(wr * 64 + mi * 16 + l15) * 40 + quad * 8];
        #pragma unroll
        for (int ni = 0; ni < 4; ++ni)
            bfr[ni] = *(const bf16x8*)&b_lds[(wc * 64 + ni * 16 + l15) * 40 + quad * 8];
        #pragma unroll
        for (int mi = 0; mi < 4; ++mi)
            #pragma unroll
            for (int ni = 0; ni < 4; ++ni)
                acc[mi][ni] = __builtin_amdgcn_mfma_f32_16x16x32_bf16(af[mi], bfr[ni], acc[mi][ni], 0, 0, 0);
        __syncthreads();
    }

    // ---- epilogue: RoPE (q,k and d<64, held entirely by wc==0 waves) ----
    bf16* outp = (section == 0 ? Qb : (section == 1 ? Kb : Vb));
    const bool do_rope = (section < 2) && (wc == 0);

    #pragma unroll
    for (int mi = 0; mi < 4; ++mi) {
        #pragma unroll
        for (int r = 0; r < 4; ++r) {
            int row_g = m0 + wr * 64 + mi * 16 + quad * 4 + r;
            int t = row_g & (T_SEQ - 1);
            int b = row_g >> 11;
            bf16* orow = outp + ((size_t)(b * NH + h) * T_SEQ + t) * HD;
            if (do_rope) {
                #pragma unroll
                for (int ni = 0; ni < 2; ++ni) {
                    int d = ni * 16 + l15;               // 0..31
                    // freq = 10000^(-d/32) = 2^(-d * log2(10000)/32)
                    float fr = exp2f(-(float)d * 0.4152412414141827f);
                    float ang = (float)t * fr;
                    float sn, cs; __sincosf(ang, &sn, &cs);
                    // accurate path: use sinf/cosf for large-arg reduction
                    sn = sinf(ang); cs = cosf(ang);
                    float ev = acc[mi][ni][r];
                    float ov = acc[mi][ni + 2][r];
                    orow[d]      = (bf16)(ev * cs - ov * sn);
                    orow[d + 32] = (bf16)(ev * sn + ov * cs);
                }
            } else {
                #pragma unroll
                for (int ni = 0; ni < 4; ++ni) {
                    int d = wc * 64 + ni * 16 + l15;
                    orow[d] = (bf16)acc[mi][ni][r];
                }
            }
        }
    }
}

// ---------------------------------------------------------------------------
// Kernel 2: causal flash attention. 64 q-rows per block (4 waves x 16 rows),
// 64-wide K/V tiles. Online softmax; P goes through LDS to re-layout
// (MFMA C-layout -> A-operand layout); V transposed into LDS at staging.
// ---------------------------------------------------------------------------
__global__ __launch_bounds__(256) void attn_kernel(
    const bf16* __restrict__ Qb, const bf16* __restrict__ Kb,
    const bf16* __restrict__ Vb, bf16* __restrict__ Ob)
{
    __shared__ bf16 k_lds[64 * 136];       // [t_kv][d], stride 136
    __shared__ bf16 vt_lds[128 * 72];      // [d][t_kv], stride 72
    __shared__ bf16 p_lds[4][16 * 72];     // per-wave P [16][64], stride 72

    const int tid = threadIdx.x, lane = tid & 63, w = tid >> 6;
    const int quad = lane >> 4, l15 = lane & 15;
    const int bx = blockIdx.x;
    const int qt = 31 - (bx >> 4);         // heavy tiles first
    const int bh = bx & 15;
    const int q0 = qt * 64;
    const int b = bh >> 3, h = bh & 7;

    // Q fragments (A-layout), held in registers for the whole block
    bf16x8 qf[4];
    const bf16* qrow = Qb + ((size_t)bh * T_SEQ + q0 + w * 16 + l15) * HD;
    #pragma unroll
    for (int kk = 0; kk < 4; ++kk)
        qf[kk] = *(const bf16x8*)(qrow + kk * 32 + quad * 8);

    f32x4 Of[8] = {};
    float m_r[4], l_r[4];
    #pragma unroll
    for (int r = 0; r < 4; ++r) { m_r[r] = -3.0e38f; l_r[r] = 0.0f; }

    for (int jt = 0; jt <= qt; ++jt) {
        const int j0 = jt * 64;
        // ---- stage K [t][d] and V transposed [d][t] ----
        {
            const int c0 = w * 32;
            const bf16* kp = Kb + ((size_t)bh * T_SEQ + j0 + lane) * HD + c0;
            #pragma unroll
            for (int ch = 0; ch < 4; ++ch)
                *(bf16x8*)&k_lds[lane * 136 + c0 + ch * 8] = *(const bf16x8*)(kp + ch * 8);
            const bf16* vp = Vb + ((size_t)bh * T_SEQ + j0 + lane) * HD + c0;
            #pragma unroll
            for (int i = 0; i < 32; ++i)
                vt_lds[(c0 + i) * 72 + lane] = vp[i];
        }
        __syncthreads();

        // ---- S = Q K^T (per wave: 16 rows x 64 cols) ----
        f32x4 sa[4] = {};
        #pragma unroll
        for (int ni = 0; ni < 4; ++ni)
            #pragma unroll
            for (int kk = 0; kk < 4; ++kk) {
                bf16x8 kb = *(const bf16x8*)&k_lds[(ni * 16 + l15) * 136 + kk * 32 + quad * 8];
                sa[ni] = __builtin_amdgcn_mfma_f32_16x16x32_bf16(qf[kk], kb, sa[ni], 0, 0, 0);
            }

        const bool diag = (jt == qt);
        #pragma unroll
        for (int r = 0; r < 4; ++r) {
            const int lrow = w * 16 + quad * 4 + r;     // local q row (0..63)
            float sv[4], mx = -3.0e38f;
            #pragma unroll
            for (int ni = 0; ni < 4; ++ni) {
                float s = sa[ni][r] * 0.0078125f;       // 1/HEAD_DIM
                if (diag && (ni * 16 + l15) > lrow) s = -1.0e30f;
                sv[ni] = s;
                mx = fmaxf(mx, s);
            }
            #pragma unroll
            for (int off = 1; off < 16; off <<= 1)
                mx = fmaxf(mx, __shfl_xor(mx, off));
            const float mnew  = fmaxf(m_r[r], mx);
            const float alpha = __expf(m_r[r] - mnew);
            float rsum = 0.0f;
            #pragma unroll
            for (int ni = 0; ni < 4; ++ni) {
                float pv = __expf(sv[ni] - mnew);
                rsum += pv;
                p_lds[w][(quad * 4 + r) * 72 + ni * 16 + l15] = (bf16)pv;
            }
            #pragma unroll
            for (int off = 1; off < 16; off <<= 1)
                rsum += __shfl_xor(rsum, off);
            l_r[r] = l_r[r] * alpha + rsum;
            m_r[r] = mnew;
            #pragma unroll
            for (int di = 0; di < 8; ++di) Of[di][r] *= alpha;
        }
        __syncthreads();

        // ---- O += P V ----
        #pragma unroll
        for (int kk = 0; kk < 2; ++kk) {
            bf16x8 pa = *(const bf16x8*)&p_lds[w][l15 * 72 + kk * 32 + quad * 8];
            #pragma unroll
            for (int di = 0; di < 8; ++di) {
                bf16x8 vb = *(const bf16x8*)&vt_lds[(di * 16 + l15) * 72 + kk * 32 + quad * 8];
                Of[di] = __builtin_amdgcn_mfma_f32_16x16x32_bf16(pa, vb, Of[di], 0, 0, 0);
            }
        }
        __syncthreads();   // protect K/V LDS before next stage
    }

    // ---- epilogue: normalize, store O bf16 [B,T,H,D] ----
    #pragma unroll
    for (int r = 0; r < 4; ++r) {
        float inv = 1.0f / l_r[r];
        int t = q0 + w * 16 + quad * 4 + r;
        bf16* op = Ob + ((size_t)(b * T_SEQ + t) * NH + h) * HD;
        #pragma unroll
        for (int di = 0; di < 8; ++di)
            op[di * 16 + l15] = (bf16)(Of[di][r] * inv);
    }
}

// ---------------------------------------------------------------------------
// Kernel 3: output projection. R[4096,1024] = O_bf16 @ wo(fp32->bf16), fp32 out.
// ---------------------------------------------------------------------------
__global__ __launch_bounds__(256) void out_proj_kernel(
    const bf16* __restrict__ Ob, const float* __restrict__ wo,
    float* __restrict__ out)
{
    __shared__ bf16 a_lds[128 * 40];
    __shared__ bf16 b_lds[128 * 40];

    const int tid = threadIdx.x;
    const int bx  = blockIdx.x;
    const int nt  = bx & 7, mt = bx >> 3;
    const int n0  = nt * 128, m0 = mt * 128;

    const int lane = tid & 63, w = tid >> 6;
    const int quad = lane >> 4, l15 = lane & 15;
    const int wr = w >> 1, wc = w & 1;

    const int am = tid & 127, ac0 = (tid >> 7) * 16;
    const int bk = tid & 31,  bc0 = (tid >> 5) * 16;

    f32x4 acc[4][4] = {};

    for (int k0 = 0; k0 < MDL; k0 += 32) {
        // stage A (already bf16)
        const bf16* ap = Ob + (size_t)(m0 + am) * MDL + k0 + ac0;
        bf16x8 v0 = *(const bf16x8*)ap;
        bf16x8 v1 = *(const bf16x8*)(ap + 8);
        *(bf16x4*)&a_lds[am * 40 + ac0 + 0]  = __builtin_shufflevector(v0, v0, 0, 1, 2, 3);
        *(bf16x4*)&a_lds[am * 40 + ac0 + 4]  = __builtin_shufflevector(v0, v0, 4, 5, 6, 7);
        *(bf16x4*)&a_lds[am * 40 + ac0 + 8]  = __builtin_shufflevector(v1, v1, 0, 1, 2, 3);
        *(bf16x4*)&a_lds[am * 40 + ac0 + 12] = __builtin_shufflevector(v1, v1, 4, 5, 6, 7);
        // stage B transposed (fp32 -> bf16)
        const float* bp = wo + (size_t)(k0 + bk) * MDL + n0 + bc0;
        #pragma unroll
        for (int i = 0; i < 4; ++i) {
            float4 v = *(const float4*)(bp + 4 * i);
            b_lds[(bc0 + 4 * i + 0) * 40 + bk] = (bf16)v.x;
            b_lds[(bc0 + 4 * i + 1) * 40 + bk] = (bf16)v.y;
            b_lds[(bc0 + 4 * i + 2) * 40 + bk] = (bf16)v.z;
            b_lds[(bc0 + 4 * i + 3) * 40 + bk] = (bf16)v.w;
        }
        __syncthreads();

        bf16x8 af[4], bfr[4];
        #pragma unroll
        for (int mi = 0; mi < 4; ++mi)
            af[mi] = *(const bf16x8*)&a_lds[(wr * 64 + mi * 16 + l15) * 40 + quad * 8];
        #pragma unroll
        for (int ni = 0; ni < 4; ++ni)
            bfr[ni] = *(const bf16x8*)&b_lds[(wc * 64 + ni * 16 + l15) * 40 + quad * 8];
        #pragma unroll
        for (int mi = 0; mi < 4; ++mi)
            #pragma unroll
            for (int ni = 0; ni < 4; ++ni)
                acc[mi][ni] = __builtin_amdgcn_mfma_f32_16x16x32_bf16(af[mi], bfr[ni], acc[mi][ni], 0, 0, 0);
        __syncthreads();
    }

    #pragma unroll
    for (int mi = 0; mi < 4; ++mi)
        #pragma unroll
        for (int r = 0; r < 4; ++r) {
            int row_g = m0 + wr * 64 + mi * 16 + quad * 4 + r;
            float* crow = out + (size_t)row_g * MDL + n0;
            #pragma unroll
            for (int ni = 0; ni < 4; ++ni)
                crow[wc * 64 + ni * 16 + l15] = acc[mi][ni][r];
        }
}

// ---------------------------------------------------------------------------
extern "C" void kernel_launch(void* const* d_in, const int* in_sizes, int n_in,
                              void* d_out, int out_size, void* d_ws, size_t ws_size,
                              hipStream_t stream) {
    const float* x  = (const float*)d_in[0];
    const float* wq = (const float*)d_in[1];
    const float* wk = (const float*)d_in[2];
    const float* wv = (const float*)d_in[3];
    const float* wo = (const float*)d_in[4];
    float* out = (float*)d_out;

    const size_t NTOK = (size_t)2 * NH * T_SEQ * HD;  // 4,194,304 elems
    bf16* Qb = (bf16*)d_ws;
    bf16* Kb = Qb + NTOK;
    bf16* Vb = Kb + NTOK;
    bf16* Ob = Vb + NTOK;

    qkv_rope_kernel<<<768, 256, 0, stream>>>(x, wq, wk, wv, Qb, Kb, Vb);
    attn_kernel<<<512, 256, 0, stream>>>(Qb, Kb, Vb, Ob);
    out_proj_kernel<<<256, 256, 0, stream>>>(Ob, wo, out);
}

// Round 2
// 318.818 us; speedup vs baseline: 2.3470x; 2.3470x over previous
//
#include <hip/hip_runtime.h>

#define T_SEQ 2048
#define MDL   1024
#define NH    8
#define HD    128

typedef __bf16 bf16;
typedef __bf16 bf16x8 __attribute__((ext_vector_type(8)));
typedef __bf16 bf16x4 __attribute__((ext_vector_type(4)));
typedef float  f32x4  __attribute__((ext_vector_type(4)));

// ---------------------------------------------------------------------------
// Kernel 1: QKV projection GEMM (fp32 inputs -> bf16 LDS tiles -> MFMA) with
// fused fractional RoPE in the epilogue. Output: Q,K,V bf16 [B,H,T,D].
// C = x[4096,1024] @ Wqkv[1024,3072]; each 128-wide n-tile is exactly one
// (section,h) pair since 1024 % 128 == 0.
// NOTE: epilogue must use ONLY inline intrinsics (__sinf/__cosf/__expf) —
// libm sinf/cosf are real calls and force the allocator to spill all 64
// accumulator regs to scratch (R1: WRITE_SIZE 1.69 GB, VGPR_Count 28).
// ---------------------------------------------------------------------------
__global__ __launch_bounds__(256) void qkv_rope_kernel(
    const float* __restrict__ x,  const float* __restrict__ wq,
    const float* __restrict__ wk, const float* __restrict__ wv,
    bf16* __restrict__ Qb, bf16* __restrict__ Kb, bf16* __restrict__ Vb)
{
    __shared__ bf16 a_lds[128 * 40];   // A tile [m][k], row stride 40 (pad)
    __shared__ bf16 b_lds[128 * 40];   // B tile transposed [n][k], stride 40

    const int tid  = threadIdx.x;
    const int bx   = blockIdx.x;
    const int nt   = bx % 24, mt = bx / 24;
    const int n0   = nt * 128, m0 = mt * 128;
    const int section = n0 >> 10;            // 0=q, 1=k, 2=v
    const int h       = (n0 & 1023) >> 7;    // head
    const float* Bg = (section == 0 ? wq : (section == 1 ? wk : wv)) + h * HD;

    const int lane = tid & 63, w = tid >> 6;
    const int quad = lane >> 4, l15 = lane & 15;
    const int wr = w >> 1, wc = w & 1;

    // staging maps
    const int am = tid & 127, ac0 = (tid >> 7) * 16;   // A: row am, 16 cols
    const int bk = tid & 31,  bc0 = (tid >> 5) * 16;   // B: k-row bk, 16 n-cols

    f32x4 acc[4][4] = {};

    for (int k0 = 0; k0 < MDL; k0 += 32) {
        // ---- stage A (fp32 -> bf16) ----
        const float* ap = x + (m0 + am) * MDL + k0 + ac0;
        #pragma unroll
        for (int i = 0; i < 4; ++i) {
            float4 v = *(const float4*)(ap + 4 * i);
            bf16x4 o; o[0] = (bf16)v.x; o[1] = (bf16)v.y; o[2] = (bf16)v.z; o[3] = (bf16)v.w;
            *(bf16x4*)&a_lds[am * 40 + ac0 + 4 * i] = o;
        }
        // ---- stage B transposed (fp32 -> bf16) ----
        const float* bp = Bg + (size_t)(k0 + bk) * MDL + bc0;
        #pragma unroll
        for (int i = 0; i < 4; ++i) {
            float4 v = *(const float4*)(bp + 4 * i);
            b_lds[(bc0 + 4 * i + 0) * 40 + bk] = (bf16)v.x;
            b_lds[(bc0 + 4 * i + 1) * 40 + bk] = (bf16)v.y;
            b_lds[(bc0 + 4 * i + 2) * 40 + bk] = (bf16)v.z;
            b_lds[(bc0 + 4 * i + 3) * 40 + bk] = (bf16)v.w;
        }
        __syncthreads();

        bf16x8 af[4], bfr[4];
        #pragma unroll
        for (int mi = 0; mi < 4; ++mi)
            af[mi] = *(const bf16x8*)&a_lds[(wr * 64 + mi * 16 + l15) * 40 + quad * 8];
        #pragma unroll
        for (int ni = 0; ni < 4; ++ni)
            bfr[ni] = *(const bf16x8*)&b_lds[(wc * 64 + ni * 16 + l15) * 40 + quad * 8];
        #pragma unroll
        for (int mi = 0; mi < 4; ++mi)
            #pragma unroll
            for (int ni = 0; ni < 4; ++ni)
                acc[mi][ni] = __builtin_amdgcn_mfma_f32_16x16x32_bf16(af[mi], bfr[ni], acc[mi][ni], 0, 0, 0);
        __syncthreads();
    }

    // ---- epilogue: RoPE (q,k and d<64, held entirely by wc==0 waves) ----
    bf16* outp = (section == 0 ? Qb : (section == 1 ? Kb : Vb));
    const bool do_rope = (section < 2) && (wc == 0);

    // freq = 10000^(-d/32) = exp(-d * ln(10000)/32); only 2 d values/thread
    float fr_n[2];
    #pragma unroll
    for (int ni = 0; ni < 2; ++ni)
        fr_n[ni] = __expf(-(float)(ni * 16 + l15) * 0.28782313662425573f);

    #pragma unroll
    for (int mi = 0; mi < 4; ++mi) {
        #pragma unroll
        for (int r = 0; r < 4; ++r) {
            int row_g = m0 + wr * 64 + mi * 16 + quad * 4 + r;
            int t = row_g & (T_SEQ - 1);
            int b = row_g >> 11;
            bf16* orow = outp + ((size_t)(b * NH + h) * T_SEQ + t) * HD;
            if (do_rope) {
                #pragma unroll
                for (int ni = 0; ni < 2; ++ni) {
                    int d = ni * 16 + l15;               // 0..31
                    float ang = (float)t * fr_n[ni];
                    float sn = __sinf(ang), cs = __cosf(ang);
                    float ev = acc[mi][ni][r];
                    float ov = acc[mi][ni + 2][r];
                    orow[d]      = (bf16)(ev * cs - ov * sn);
                    orow[d + 32] = (bf16)(ev * sn + ov * cs);
                }
            } else {
                #pragma unroll
                for (int ni = 0; ni < 4; ++ni) {
                    int d = wc * 64 + ni * 16 + l15;
                    orow[d] = (bf16)acc[mi][ni][r];
                }
            }
        }
    }
}

// ---------------------------------------------------------------------------
// Kernel 2: causal flash attention. 64 q-rows per block (4 waves x 16 rows),
// 64-wide K/V tiles. Online softmax; P goes through LDS to re-layout
// (MFMA C-layout -> A-operand layout); V transposed into LDS at staging.
// ---------------------------------------------------------------------------
__global__ __launch_bounds__(256) void attn_kernel(
    const bf16* __restrict__ Qb, const bf16* __restrict__ Kb,
    const bf16* __restrict__ Vb, bf16* __restrict__ Ob)
{
    __shared__ bf16 k_lds[64 * 136];       // [t_kv][d], stride 136
    __shared__ bf16 vt_lds[128 * 72];      // [d][t_kv], stride 72
    __shared__ bf16 p_lds[4][16 * 72];     // per-wave P [16][64], stride 72

    const int tid = threadIdx.x, lane = tid & 63, w = tid >> 6;
    const int quad = lane >> 4, l15 = lane & 15;
    const int bx = blockIdx.x;
    const int qt = 31 - (bx >> 4);         // heavy tiles first
    const int bh = bx & 15;
    const int q0 = qt * 64;
    const int b = bh >> 3, h = bh & 7;

    // Q fragments (A-layout), held in registers for the whole block
    bf16x8 qf[4];
    const bf16* qrow = Qb + ((size_t)bh * T_SEQ + q0 + w * 16 + l15) * HD;
    #pragma unroll
    for (int kk = 0; kk < 4; ++kk)
        qf[kk] = *(const bf16x8*)(qrow + kk * 32 + quad * 8);

    f32x4 Of[8] = {};
    float m_r[4], l_r[4];
    #pragma unroll
    for (int r = 0; r < 4; ++r) { m_r[r] = -3.0e38f; l_r[r] = 0.0f; }

    for (int jt = 0; jt <= qt; ++jt) {
        const int j0 = jt * 64;
        // ---- stage K [t][d] and V transposed [d][t] ----
        {
            const int c0 = w * 32;
            const bf16* kp = Kb + ((size_t)bh * T_SEQ + j0 + lane) * HD + c0;
            #pragma unroll
            for (int ch = 0; ch < 4; ++ch)
                *(bf16x8*)&k_lds[lane * 136 + c0 + ch * 8] = *(const bf16x8*)(kp + ch * 8);
            const bf16* vp = Vb + ((size_t)bh * T_SEQ + j0 + lane) * HD + c0;
            #pragma unroll
            for (int i = 0; i < 32; ++i)
                vt_lds[(c0 + i) * 72 + lane] = vp[i];
        }
        __syncthreads();

        // ---- S = Q K^T (per wave: 16 rows x 64 cols) ----
        f32x4 sa[4] = {};
        #pragma unroll
        for (int ni = 0; ni < 4; ++ni)
            #pragma unroll
            for (int kk = 0; kk < 4; ++kk) {
                bf16x8 kb = *(const bf16x8*)&k_lds[(ni * 16 + l15) * 136 + kk * 32 + quad * 8];
                sa[ni] = __builtin_amdgcn_mfma_f32_16x16x32_bf16(qf[kk], kb, sa[ni], 0, 0, 0);
            }

        const bool diag = (jt == qt);
        #pragma unroll
        for (int r = 0; r < 4; ++r) {
            const int lrow = w * 16 + quad * 4 + r;     // local q row (0..63)
            float sv[4], mx = -3.0e38f;
            #pragma unroll
            for (int ni = 0; ni < 4; ++ni) {
                float s = sa[ni][r] * 0.0078125f;       // 1/HEAD_DIM
                if (diag && (ni * 16 + l15) > lrow) s = -1.0e30f;
                sv[ni] = s;
                mx = fmaxf(mx, s);
            }
            #pragma unroll
            for (int off = 1; off < 16; off <<= 1)
                mx = fmaxf(mx, __shfl_xor(mx, off));
            const float mnew  = fmaxf(m_r[r], mx);
            const float alpha = __expf(m_r[r] - mnew);
            float rsum = 0.0f;
            #pragma unroll
            for (int ni = 0; ni < 4; ++ni) {
                float pv = __expf(sv[ni] - mnew);
                rsum += pv;
                p_lds[w][(quad * 4 + r) * 72 + ni * 16 + l15] = (bf16)pv;
            }
            #pragma unroll
            for (int off = 1; off < 16; off <<= 1)
                rsum += __shfl_xor(rsum, off);
            l_r[r] = l_r[r] * alpha + rsum;
            m_r[r] = mnew;
            #pragma unroll
            for (int di = 0; di < 8; ++di) Of[di][r] *= alpha;
        }
        __syncthreads();

        // ---- O += P V ----
        #pragma unroll
        for (int kk = 0; kk < 2; ++kk) {
            bf16x8 pa = *(const bf16x8*)&p_lds[w][l15 * 72 + kk * 32 + quad * 8];
            #pragma unroll
            for (int di = 0; di < 8; ++di) {
                bf16x8 vb = *(const bf16x8*)&vt_lds[(di * 16 + l15) * 72 + kk * 32 + quad * 8];
                Of[di] = __builtin_amdgcn_mfma_f32_16x16x32_bf16(pa, vb, Of[di], 0, 0, 0);
            }
        }
        __syncthreads();   // protect K/V LDS before next stage
    }

    // ---- epilogue: normalize, store O bf16 [B,T,H,D] ----
    #pragma unroll
    for (int r = 0; r < 4; ++r) {
        float inv = 1.0f / l_r[r];
        int t = q0 + w * 16 + quad * 4 + r;
        bf16* op = Ob + ((size_t)(b * T_SEQ + t) * NH + h) * HD;
        #pragma unroll
        for (int di = 0; di < 8; ++di)
            op[di * 16 + l15] = (bf16)(Of[di][r] * inv);
    }
}

// ---------------------------------------------------------------------------
// Kernel 3: output projection. R[4096,1024] = O_bf16 @ wo(fp32->bf16), fp32 out.
// ---------------------------------------------------------------------------
__global__ __launch_bounds__(256) void out_proj_kernel(
    const bf16* __restrict__ Ob, const float* __restrict__ wo,
    float* __restrict__ out)
{
    __shared__ bf16 a_lds[128 * 40];
    __shared__ bf16 b_lds[128 * 40];

    const int tid = threadIdx.x;
    const int bx  = blockIdx.x;
    const int nt  = bx & 7, mt = bx >> 3;
    const int n0  = nt * 128, m0 = mt * 128;

    const int lane = tid & 63, w = tid >> 6;
    const int quad = lane >> 4, l15 = lane & 15;
    const int wr = w >> 1, wc = w & 1;

    const int am = tid & 127, ac0 = (tid >> 7) * 16;
    const int bk = tid & 31,  bc0 = (tid >> 5) * 16;

    f32x4 acc[4][4] = {};

    for (int k0 = 0; k0 < MDL; k0 += 32) {
        // stage A (already bf16)
        const bf16* ap = Ob + (size_t)(m0 + am) * MDL + k0 + ac0;
        bf16x8 v0 = *(const bf16x8*)ap;
        bf16x8 v1 = *(const bf16x8*)(ap + 8);
        *(bf16x4*)&a_lds[am * 40 + ac0 + 0]  = __builtin_shufflevector(v0, v0, 0, 1, 2, 3);
        *(bf16x4*)&a_lds[am * 40 + ac0 + 4]  = __builtin_shufflevector(v0, v0, 4, 5, 6, 7);
        *(bf16x4*)&a_lds[am * 40 + ac0 + 8]  = __builtin_shufflevector(v1, v1, 0, 1, 2, 3);
        *(bf16x4*)&a_lds[am * 40 + ac0 + 12] = __builtin_shufflevector(v1, v1, 4, 5, 6, 7);
        // stage B transposed (fp32 -> bf16)
        const float* bp = wo + (size_t)(k0 + bk) * MDL + n0 + bc0;
        #pragma unroll
        for (int i = 0; i < 4; ++i) {
            float4 v = *(const float4*)(bp + 4 * i);
            b_lds[(bc0 + 4 * i + 0) * 40 + bk] = (bf16)v.x;
            b_lds[(bc0 + 4 * i + 1) * 40 + bk] = (bf16)v.y;
            b_lds[(bc0 + 4 * i + 2) * 40 + bk] = (bf16)v.z;
            b_lds[(bc0 + 4 * i + 3) * 40 + bk] = (bf16)v.w;
        }
        __syncthreads();

        bf16x8 af[4], bfr[4];
        #pragma unroll
        for (int mi = 0; mi < 4; ++mi)
            af[mi] = *(const bf16x8*)&a_lds[(wr * 64 + mi * 16 + l15) * 40 + quad * 8];
        #pragma unroll
        for (int ni = 0; ni < 4; ++ni)
            bfr[ni] = *(const bf16x8*)&b_lds[(wc * 64 + ni * 16 + l15) * 40 + quad * 8];
        #pragma unroll
        for (int mi = 0; mi < 4; ++mi)
            #pragma unroll
            for (int ni = 0; ni < 4; ++ni)
                acc[mi][ni] = __builtin_amdgcn_mfma_f32_16x16x32_bf16(af[mi], bfr[ni], acc[mi][ni], 0, 0, 0);
        __syncthreads();
    }

    #pragma unroll
    for (int mi = 0; mi < 4; ++mi)
        #pragma unroll
        for (int r = 0; r < 4; ++r) {
            int row_g = m0 + wr * 64 + mi * 16 + quad * 4 + r;
            float* crow = out + (size_t)row_g * MDL + n0;
            #pragma unroll
            for (int ni = 0; ni < 4; ++ni)
                crow[wc * 64 + ni * 16 + l15] = acc[mi][ni][r];
        }
}

// ---------------------------------------------------------------------------
extern "C" void kernel_launch(void* const* d_in, const int* in_sizes, int n_in,
                              void* d_out, int out_size, void* d_ws, size_t ws_size,
                              hipStream_t stream) {
    const float* x  = (const float*)d_in[0];
    const float* wq = (const float*)d_in[1];
    const float* wk = (const float*)d_in[2];
    const float* wv = (const float*)d_in[3];
    const float* wo = (const float*)d_in[4];
    float* out = (float*)d_out;

    const size_t NTOK = (size_t)2 * NH * T_SEQ * HD;  // 4,194,304 elems
    bf16* Qb = (bf16*)d_ws;
    bf16* Kb = Qb + NTOK;
    bf16* Vb = Kb + NTOK;
    bf16* Ob = Vb + NTOK;

    qkv_rope_kernel<<<768, 256, 0, stream>>>(x, wq, wk, wv, Qb, Kb, Vb);
    attn_kernel<<<512, 256, 0, stream>>>(Qb, Kb, Vb, Ob);
    out_proj_kernel<<<256, 256, 0, stream>>>(Ob, wo, out);
}

// Round 3
// 236.568 us; speedup vs baseline: 3.1630x; 1.3477x over previous
//
#include <hip/hip_runtime.h>

#define T_SEQ 2048
#define MDL   1024
#define NH    8
#define HD    128

typedef __bf16 bf16;
typedef __bf16 bf16x8 __attribute__((ext_vector_type(8)));
typedef __bf16 bf16x4 __attribute__((ext_vector_type(4)));
typedef float  f32x4  __attribute__((ext_vector_type(4)));

#define GLB(p) ((const __attribute__((address_space(1))) void*)(p))
#define LDS(p) ((__attribute__((address_space(3))) void*)(p))

// ---------------------------------------------------------------------------
// Prep A: x fp32 -> bf16 (elementwise). 4M elems, 8/thread.
// ---------------------------------------------------------------------------
__global__ __launch_bounds__(256) void convert_x_kernel(
    const float* __restrict__ x, bf16* __restrict__ xb)
{
    size_t i = ((size_t)blockIdx.x * 256 + threadIdx.x) * 8;
    float4 v0 = *(const float4*)(x + i);
    float4 v1 = *(const float4*)(x + i + 4);
    bf16x8 o;
    o[0]=(bf16)v0.x; o[1]=(bf16)v0.y; o[2]=(bf16)v0.z; o[3]=(bf16)v0.w;
    o[4]=(bf16)v1.x; o[5]=(bf16)v1.y; o[6]=(bf16)v1.z; o[7]=(bf16)v1.w;
    *(bf16x8*)(xb + i) = o;
}

// ---------------------------------------------------------------------------
// Prep B: transpose-convert weights to bf16 B^T (n-major, k-contiguous).
// Sections 0-2: wq/wk/wv [k][n] -> Wt[sec*1024 + n][k]; section 3: wo -> Wot.
// 64x64 tiles through LDS.
// ---------------------------------------------------------------------------
__global__ __launch_bounds__(256) void transpose_w_kernel(
    const float* __restrict__ wq, const float* __restrict__ wk,
    const float* __restrict__ wv, const float* __restrict__ wo,
    bf16* __restrict__ Wt, bf16* __restrict__ Wot)
{
    __shared__ bf16 t_lds[64 * 72];
    const int bx = blockIdx.x;
    const int sec = bx >> 8;           // 0..3
    const int tile = bx & 255;         // 16x16 tiles of 64x64
    const int k0 = (tile >> 4) * 64, n0 = (tile & 15) * 64;
    const float* src = sec == 0 ? wq : sec == 1 ? wk : sec == 2 ? wv : wo;
    bf16* dst = sec < 3 ? (Wt + (size_t)sec * MDL * MDL) : Wot;

    const int tid = threadIdx.x;
    const int ir = tid >> 2, jc = (tid & 3) * 16;
    const float* sp = src + (size_t)(k0 + ir) * MDL + n0 + jc;
    #pragma unroll
    for (int c = 0; c < 4; ++c) {
        float4 v = *(const float4*)(sp + c * 4);
        bf16x4 o; o[0]=(bf16)v.x; o[1]=(bf16)v.y; o[2]=(bf16)v.z; o[3]=(bf16)v.w;
        *(bf16x4*)&t_lds[ir * 72 + jc + c * 4] = o;
    }
    __syncthreads();
    bf16x8 o0, o1;
    #pragma unroll
    for (int jj = 0; jj < 8; ++jj) {
        o0[jj] = t_lds[(jc + jj) * 72 + ir];
        o1[jj] = t_lds[(jc + 8 + jj) * 72 + ir];
    }
    bf16* dp = dst + (size_t)(n0 + ir) * MDL + k0 + jc;
    *(bf16x8*)dp = o0;
    *(bf16x8*)(dp + 8) = o1;
}

// ---------------------------------------------------------------------------
// Kernel 1: QKV GEMM, m97 structure: 128x128 tile, BK=32, global_load_lds
// width-16 into unpadded stride-32 LDS, ds_read_b128 fragments, 16 MFMA/step.
// Fused fractional RoPE epilogue. Output Q,K,V bf16 [B,H,T,D].
// ---------------------------------------------------------------------------
__global__ __launch_bounds__(256) void qkv_rope_kernel(
    const bf16* __restrict__ xb, const bf16* __restrict__ Wt,
    bf16* __restrict__ Qb, bf16* __restrict__ Kb, bf16* __restrict__ Vb)
{
    __shared__ bf16 a_lds[128 * 32];   // [m][k] unpadded (global_load_lds dest)
    __shared__ bf16 b_lds[128 * 32];   // [n][k] unpadded

    const int tid = threadIdx.x, bx = blockIdx.x;
    const int nt = bx % 24, mt = bx / 24;
    const int n0 = nt * 128, m0 = mt * 128;
    const int section = n0 >> 10;
    const int h = (n0 & 1023) >> 7;

    const int lane = tid & 63, w = tid >> 6;
    const int quad = lane >> 4, l15 = lane & 15;
    const int wr = w >> 1, wc = w & 1;
    const int lrow = lane >> 2, lsub = lane & 3;   // staging: 4 lanes/row

    const bf16* gA = xb + (size_t)m0 * MDL + lsub * 8;
    const bf16* gB = Wt + (size_t)n0 * MDL + lsub * 8;

    f32x4 acc[4][4] = {};

    for (int k0 = 0; k0 < MDL; k0 += 32) {
        #pragma unroll
        for (int i = 0; i < 2; ++i) {
            const int ch = w * 2 + i;              // 16-row chunk 0..7
            const int row = ch * 16 + lrow;
            __builtin_amdgcn_global_load_lds(GLB(gA + (size_t)row * MDL + k0),
                                             LDS(&a_lds[ch * 16 * 32]), 16, 0, 0);
            __builtin_amdgcn_global_load_lds(GLB(gB + (size_t)row * MDL + k0),
                                             LDS(&b_lds[ch * 16 * 32]), 16, 0, 0);
        }
        __syncthreads();

        bf16x8 af[4], bfr[4];
        #pragma unroll
        for (int mi = 0; mi < 4; ++mi)
            af[mi] = *(const bf16x8*)&a_lds[(wr * 64 + mi * 16 + l15) * 32 + quad * 8];
        #pragma unroll
        for (int ni = 0; ni < 4; ++ni)
            bfr[ni] = *(const bf16x8*)&b_lds[(wc * 64 + ni * 16 + l15) * 32 + quad * 8];
        #pragma unroll
        for (int mi = 0; mi < 4; ++mi)
            #pragma unroll
            for (int ni = 0; ni < 4; ++ni)
                acc[mi][ni] = __builtin_amdgcn_mfma_f32_16x16x32_bf16(af[mi], bfr[ni], acc[mi][ni], 0, 0, 0);
        __syncthreads();
    }

    // ---- epilogue: RoPE (q,k sections, d<64 held by wc==0 waves) ----
    bf16* outp = (section == 0 ? Qb : (section == 1 ? Kb : Vb));
    const bool do_rope = (section < 2) && (wc == 0);

    float fr_n[2];
    #pragma unroll
    for (int ni = 0; ni < 2; ++ni)
        fr_n[ni] = __expf(-(float)(ni * 16 + l15) * 0.28782313662425573f);

    #pragma unroll
    for (int mi = 0; mi < 4; ++mi) {
        #pragma unroll
        for (int r = 0; r < 4; ++r) {
            int row_g = m0 + wr * 64 + mi * 16 + quad * 4 + r;
            int t = row_g & (T_SEQ - 1);
            int b = row_g >> 11;
            bf16* orow = outp + ((size_t)(b * NH + h) * T_SEQ + t) * HD;
            if (do_rope) {
                #pragma unroll
                for (int ni = 0; ni < 2; ++ni) {
                    int d = ni * 16 + l15;
                    float ang = (float)t * fr_n[ni];
                    float sn = __sinf(ang), cs = __cosf(ang);
                    float ev = acc[mi][ni][r];
                    float ov = acc[mi][ni + 2][r];
                    orow[d]      = (bf16)(ev * cs - ov * sn);
                    orow[d + 32] = (bf16)(ev * sn + ov * cs);
                }
            } else {
                #pragma unroll
                for (int ni = 0; ni < 4; ++ni) {
                    int d = wc * 64 + ni * 16 + l15;
                    orow[d] = (bf16)acc[mi][ni][r];
                }
            }
        }
    }
}

// ---------------------------------------------------------------------------
// Kernel 2: causal flash attention (unchanged from R2 — gets next counters).
// ---------------------------------------------------------------------------
__global__ __launch_bounds__(256) void attn_kernel(
    const bf16* __restrict__ Qb, const bf16* __restrict__ Kb,
    const bf16* __restrict__ Vb, bf16* __restrict__ Ob)
{
    __shared__ bf16 k_lds[64 * 136];
    __shared__ bf16 vt_lds[128 * 72];
    __shared__ bf16 p_lds[4][16 * 72];

    const int tid = threadIdx.x, lane = tid & 63, w = tid >> 6;
    const int quad = lane >> 4, l15 = lane & 15;
    const int bx = blockIdx.x;
    const int qt = 31 - (bx >> 4);
    const int bh = bx & 15;
    const int q0 = qt * 64;
    const int b = bh >> 3, h = bh & 7;

    bf16x8 qf[4];
    const bf16* qrow = Qb + ((size_t)bh * T_SEQ + q0 + w * 16 + l15) * HD;
    #pragma unroll
    for (int kk = 0; kk < 4; ++kk)
        qf[kk] = *(const bf16x8*)(qrow + kk * 32 + quad * 8);

    f32x4 Of[8] = {};
    float m_r[4], l_r[4];
    #pragma unroll
    for (int r = 0; r < 4; ++r) { m_r[r] = -3.0e38f; l_r[r] = 0.0f; }

    for (int jt = 0; jt <= qt; ++jt) {
        const int j0 = jt * 64;
        {
            const int c0 = w * 32;
            const bf16* kp = Kb + ((size_t)bh * T_SEQ + j0 + lane) * HD + c0;
            #pragma unroll
            for (int ch = 0; ch < 4; ++ch)
                *(bf16x8*)&k_lds[lane * 136 + c0 + ch * 8] = *(const bf16x8*)(kp + ch * 8);
            const bf16* vp = Vb + ((size_t)bh * T_SEQ + j0 + lane) * HD + c0;
            #pragma unroll
            for (int i = 0; i < 32; ++i)
                vt_lds[(c0 + i) * 72 + lane] = vp[i];
        }
        __syncthreads();

        f32x4 sa[4] = {};
        #pragma unroll
        for (int ni = 0; ni < 4; ++ni)
            #pragma unroll
            for (int kk = 0; kk < 4; ++kk) {
                bf16x8 kb = *(const bf16x8*)&k_lds[(ni * 16 + l15) * 136 + kk * 32 + quad * 8];
                sa[ni] = __builtin_amdgcn_mfma_f32_16x16x32_bf16(qf[kk], kb, sa[ni], 0, 0, 0);
            }

        const bool diag = (jt == qt);
        #pragma unroll
        for (int r = 0; r < 4; ++r) {
            const int lrow = w * 16 + quad * 4 + r;
            float sv[4], mx = -3.0e38f;
            #pragma unroll
            for (int ni = 0; ni < 4; ++ni) {
                float s = sa[ni][r] * 0.0078125f;
                if (diag && (ni * 16 + l15) > lrow) s = -1.0e30f;
                sv[ni] = s;
                mx = fmaxf(mx, s);
            }
            #pragma unroll
            for (int off = 1; off < 16; off <<= 1)
                mx = fmaxf(mx, __shfl_xor(mx, off));
            const float mnew  = fmaxf(m_r[r], mx);
            const float alpha = __expf(m_r[r] - mnew);
            float rsum = 0.0f;
            #pragma unroll
            for (int ni = 0; ni < 4; ++ni) {
                float pv = __expf(sv[ni] - mnew);
                rsum += pv;
                p_lds[w][(quad * 4 + r) * 72 + ni * 16 + l15] = (bf16)pv;
            }
            #pragma unroll
            for (int off = 1; off < 16; off <<= 1)
                rsum += __shfl_xor(rsum, off);
            l_r[r] = l_r[r] * alpha + rsum;
            m_r[r] = mnew;
            #pragma unroll
            for (int di = 0; di < 8; ++di) Of[di][r] *= alpha;
        }
        __syncthreads();

        #pragma unroll
        for (int kk = 0; kk < 2; ++kk) {
            bf16x8 pa = *(const bf16x8*)&p_lds[w][l15 * 72 + kk * 32 + quad * 8];
            #pragma unroll
            for (int di = 0; di < 8; ++di) {
                bf16x8 vb = *(const bf16x8*)&vt_lds[(di * 16 + l15) * 72 + kk * 32 + quad * 8];
                Of[di] = __builtin_amdgcn_mfma_f32_16x16x32_bf16(pa, vb, Of[di], 0, 0, 0);
            }
        }
        __syncthreads();
    }

    #pragma unroll
    for (int r = 0; r < 4; ++r) {
        float inv = 1.0f / l_r[r];
        int t = q0 + w * 16 + quad * 4 + r;
        bf16* op = Ob + ((size_t)(b * T_SEQ + t) * NH + h) * HD;
        #pragma unroll
        for (int di = 0; di < 8; ++di)
            op[di * 16 + l15] = (bf16)(Of[di][r] * inv);
    }
}

// ---------------------------------------------------------------------------
// Kernel 3: output projection, m97 structure. R = Ob @ Wot^T, fp32 out.
// ---------------------------------------------------------------------------
__global__ __launch_bounds__(256) void out_proj_kernel(
    const bf16* __restrict__ Ob, const bf16* __restrict__ Wot,
    float* __restrict__ out)
{
    __shared__ bf16 a_lds[128 * 32];
    __shared__ bf16 b_lds[128 * 32];

    const int tid = threadIdx.x, bx = blockIdx.x;
    const int nt = bx & 7, mt = bx >> 3;
    const int n0 = nt * 128, m0 = mt * 128;

    const int lane = tid & 63, w = tid >> 6;
    const int quad = lane >> 4, l15 = lane & 15;
    const int wr = w >> 1, wc = w & 1;
    const int lrow = lane >> 2, lsub = lane & 3;

    const bf16* gA = Ob  + (size_t)m0 * MDL + lsub * 8;
    const bf16* gB = Wot + (size_t)n0 * MDL + lsub * 8;

    f32x4 acc[4][4] = {};

    for (int k0 = 0; k0 < MDL; k0 += 32) {
        #pragma unroll
        for (int i = 0; i < 2; ++i) {
            const int ch = w * 2 + i;
            const int row = ch * 16 + lrow;
            __builtin_amdgcn_global_load_lds(GLB(gA + (size_t)row * MDL + k0),
                                             LDS(&a_lds[ch * 16 * 32]), 16, 0, 0);
            __builtin_amdgcn_global_load_lds(GLB(gB + (size_t)row * MDL + k0),
                                             LDS(&b_lds[ch * 16 * 32]), 16, 0, 0);
        }
        __syncthreads();

        bf16x8 af[4], bfr[4];
        #pragma unroll
        for (int mi = 0; mi < 4; ++mi)
            af[mi] = *(const bf16x8*)&a_lds[(wr * 64 + mi * 16 + l15) * 32 + quad * 8];
        #pragma unroll
        for (int ni = 0; ni < 4; ++ni)
            bfr[ni] = *(const bf16x8*)&b_lds[(wc * 64 + ni * 16 + l15) * 32 + quad * 8];
        #pragma unroll
        for (int mi = 0; mi < 4; ++mi)
            #pragma unroll
            for (int ni = 0; ni < 4; ++ni)
                acc[mi][ni] = __builtin_amdgcn_mfma_f32_16x16x32_bf16(af[mi], bfr[ni], acc[mi][ni], 0, 0, 0);
        __syncthreads();
    }

    #pragma unroll
    for (int mi = 0; mi < 4; ++mi)
        #pragma unroll
        for (int r = 0; r < 4; ++r) {
            int row_g = m0 + wr * 64 + mi * 16 + quad * 4 + r;
            float* crow = out + (size_t)row_g * MDL + n0;
            #pragma unroll
            for (int ni = 0; ni < 4; ++ni)
                crow[wc * 64 + ni * 16 + l15] = acc[mi][ni][r];
        }
}

// ---------------------------------------------------------------------------
extern "C" void kernel_launch(void* const* d_in, const int* in_sizes, int n_in,
                              void* d_out, int out_size, void* d_ws, size_t ws_size,
                              hipStream_t stream) {
    const float* x  = (const float*)d_in[0];
    const float* wq = (const float*)d_in[1];
    const float* wk = (const float*)d_in[2];
    const float* wv = (const float*)d_in[3];
    const float* wo = (const float*)d_in[4];
    float* out = (float*)d_out;

    const size_t NTOK = (size_t)2 * NH * T_SEQ * HD;  // 4,194,304 elems
    bf16* Qb  = (bf16*)d_ws;
    bf16* Kb  = Qb + NTOK;
    bf16* Vb  = Kb + NTOK;
    bf16* Ob  = Vb + NTOK;
    bf16* xb  = Ob + NTOK;                      // [4096][1024]
    bf16* Wt  = xb + (size_t)4096 * MDL;        // [3072][1024]
    bf16* Wot = Wt + (size_t)3 * MDL * MDL;     // [1024][1024]

    transpose_w_kernel<<<1024, 256, 0, stream>>>(wq, wk, wv, wo, Wt, Wot);
    convert_x_kernel<<<2048, 256, 0, stream>>>(x, xb);
    qkv_rope_kernel<<<768, 256, 0, stream>>>(xb, Wt, Qb, Kb, Vb);
    attn_kernel<<<512, 256, 0, stream>>>(Qb, Kb, Vb, Ob);
    out_proj_kernel<<<256, 256, 0, stream>>>(Ob, Wot, out);
}